// Round 3
// baseline (26.730 us; speedup 1.0000x reference)
//
#include <hip/hip_runtime.h>
#include <hip/hip_bf16.h>

#define INV2PI 0.15915494309189535f

// Chebyshev positional embedding, d_model == 1024 fast path.
// out[row, n] = T_n(x) = cos(n * acos(x)), x = 2*id/max_seq_len - 1.
// One wave per row-iteration; lane l owns n = 256*q + 4*l + {0..3} so each
// float4 store is a perfectly lane-coalesced 1 KB block. The 4 q-clusters use
// independently-computed base angles (hw v_sin/v_cos, REVOLUTIONS + fract
// reduction) -> 4 independent short chains, good ILP. Grid-stride over rows
// (2048 blocks = 8/CU) so successive rows overlap compute with stores.
__global__ void __launch_bounds__(256)
cheb1024_kernel(const float* __restrict__ ids,
                const int* __restrict__ p_maxlen,
                float* __restrict__ out,
                int n_rows) {
    const float inv = 2.0f / (float)(*p_maxlen);
    const int wave = threadIdx.x >> 6;
    const int lane = threadIdx.x & 63;
    const int waves_per_blk = blockDim.x >> 6;
    const int nwaves = gridDim.x * waves_per_blk;

    for (int row = blockIdx.x * waves_per_blk + wave; row < n_rows; row += nwaves) {
        float x = fmaf(ids[row], inv, -1.0f);
        x = fminf(fmaxf(x, -1.0f), 1.0f);                  // acos domain guard
        const float sx = sqrtf(fmaxf(0.0f, 1.0f - x * x)); // sin(theta) >= 0
        const float trev = acosf(x) * INV2PI;              // theta in revolutions

        float* rowp = out + (size_t)row * 1024 + 4 * lane;
        const float base = (float)(4 * lane) * trev;

#pragma unroll
        for (int q = 0; q < 4; ++q) {
            float a = fmaf((float)(256 * q), trev, base);  // (4*lane + 256*q)*theta (rev)
            a -= floorf(a);                                // fract-reduce for hw trig
            const float c0 = __builtin_amdgcn_cosf(a);
            const float s0 = __builtin_amdgcn_sinf(a);
            // rotate by theta: (c,s) -> (c*x - s*sx, s*x + c*sx)
            const float c1 = fmaf(c0, x, -(s0 * sx));
            const float s1 = fmaf(s0, x,  (c0 * sx));
            const float c2 = fmaf(c1, x, -(s1 * sx));
            const float s2 = fmaf(s1, x,  (c1 * sx));
            const float c3 = fmaf(c2, x, -(s2 * sx));
            *(float4*)(rowp + q * 256) = make_float4(c0, c1, c2, c3);
        }
    }
}

// Generic fallback (any d_model % 8 == 0).
__global__ void __launch_bounds__(256)
cheb_generic_kernel(const float* __restrict__ ids,
                    const int* __restrict__ p_maxlen,
                    float* __restrict__ out,
                    int n_rows, int d_model) {
    const float inv = 2.0f / (float)(*p_maxlen);
    const int per_row = d_model >> 3;
    const long long total = (long long)n_rows * per_row;
    const long long stride = (long long)gridDim.x * blockDim.x;
    for (long long tid = (long long)blockIdx.x * blockDim.x + threadIdx.x;
         tid < total; tid += stride) {
        const int row = (int)(tid / per_row);
        const int seg = (int)(tid - (long long)row * per_row);

        float x = fmaf(ids[row], inv, -1.0f);
        x = fminf(fmaxf(x, -1.0f), 1.0f);
        const float sx = sqrtf(fmaxf(0.0f, 1.0f - x * x));
        const float theta = acosf(x);

        float c, s;
        sincosf((float)(seg << 3) * theta, &s, &c);

        float v[8];
#pragma unroll
        for (int k = 0; k < 8; ++k) {
            v[k] = c;
            const float nc = fmaf(c, x, -(s * sx));
            const float ns = fmaf(s, x,  (c * sx));
            c = nc; s = ns;
        }
        float4* o = (float4*)(out + tid * 8);
        o[0] = make_float4(v[0], v[1], v[2], v[3]);
        o[1] = make_float4(v[4], v[5], v[6], v[7]);
    }
}

extern "C" void kernel_launch(void* const* d_in, const int* in_sizes, int n_in,
                              void* d_out, int out_size, void* d_ws, size_t ws_size,
                              hipStream_t stream) {
    const float* ids     = (const float*)d_in[0];
    const int*   pmaxlen = (const int*)d_in[1];
    float*       out     = (float*)d_out;

    const int n_rows  = in_sizes[0];           // B*S = 32768
    const int d_model = out_size / n_rows;     // 1024

    if (d_model == 1024) {
        // 2048 blocks x 4 waves = 8192 waves; 32768 rows -> 4 rows/wave,
        // 8 blocks/CU -> full 32-waves/CU occupancy.
        int blocks = 2048;
        const int max_needed = (n_rows + 3) / 4;
        if (blocks > max_needed) blocks = max_needed;
        cheb1024_kernel<<<blocks, 256, 0, stream>>>(ids, pmaxlen, out, n_rows);
    } else {
        const long long total = (long long)n_rows * (d_model >> 3);
        int blocks = (int)((total + 255) / 256);
        if (blocks > 16384) blocks = 16384;
        cheb_generic_kernel<<<blocks, 256, 0, stream>>>(ids, pmaxlen, out, n_rows, d_model);
    }
}